// Round 13
// baseline (67.932 us; speedup 1.0000x reference)
//
#include <hip/hip_runtime.h>

#define TT 768
#define KD 512
#define NC 1024
#define RLN2_2 2.8853900817779268f   // 2/ln(2)

typedef short short8 __attribute__((ext_vector_type(8)));
typedef float f32x4  __attribute__((ext_vector_type(4)));
typedef float f32x2  __attribute__((ext_vector_type(2)));

__device__ __forceinline__ float fast_exp2(float x) {
#if __has_builtin(__builtin_amdgcn_exp2f)
    return __builtin_amdgcn_exp2f(x);
#else
    return exp2f(x);
#endif
}
__device__ __forceinline__ float fast_rcp(float x) {
#if __has_builtin(__builtin_amdgcn_rcpf)
    return __builtin_amdgcn_rcpf(x);
#else
    return 1.0f / x;
#endif
}
__device__ __forceinline__ float fast_tanh(float x) {
    float e = fast_exp2(x * RLN2_2);
    return fmaf(-2.0f, fast_rcp(e + 1.0f), 1.0f);
}
__device__ __forceinline__ ushort f2bf(float f) {   // RNE f32->bf16
    uint u = __float_as_uint(f);
    u += 0x7fff + ((u >> 16) & 1);
    return (ushort)(u >> 16);
}

// ---------------------------------------------------------------------------
// Prep: x->bf16; foh/fom -> [c][k] bf16; hid2 -> [n][k] bf16 (transposes)
// ---------------------------------------------------------------------------
__global__ __launch_bounds__(256) void k_prep(
    const float* __restrict__ x, const float* __restrict__ foh,
    const float* __restrict__ fom, const float* __restrict__ hid2,
    ushort* __restrict__ xb, ushort* __restrict__ b1t, ushort* __restrict__ h2t)
{
    const int b = blockIdx.x, t = threadIdx.x;
    if (b < 96) {
        int base = b * 4096 + t * 16;
        #pragma unroll
        for (int q = 0; q < 4; ++q) {
            float4 v = *(const float4*)&x[base + q * 4];
            ushort4 o; o.x = f2bf(v.x); o.y = f2bf(v.y); o.z = f2bf(v.z); o.w = f2bf(v.w);
            *(ushort4*)&xb[base + q * 4] = o;
        }
        return;
    }
    __shared__ float tile[64][65];
    const float* src; ushort* dst; int R, C, r0, c0;
    if (b < 160)      { int bb = b - 96;  src = foh;  dst = b1t;             R = 512;  C = 512; r0 = (bb >> 3) * 64; c0 = (bb & 7) * 64; }
    else if (b < 224) { int bb = b - 160; src = fom;  dst = b1t + 512 * 512; R = 512;  C = 512; r0 = (bb >> 3) * 64; c0 = (bb & 7) * 64; }
    else              { int bb = b - 224; src = hid2; dst = h2t;             R = 1024; C = 512; r0 = (bb >> 3) * 64; c0 = (bb & 7) * 64; }
    const int ty = t >> 4, tx = t & 15;
    #pragma unroll
    for (int q = 0; q < 4; ++q) {
        float4 v = *(const float4*)&src[(r0 + ty + q * 16) * C + c0 + tx * 4];
        tile[ty + q * 16][tx * 4 + 0] = v.x;
        tile[ty + q * 16][tx * 4 + 1] = v.y;
        tile[ty + q * 16][tx * 4 + 2] = v.z;
        tile[ty + q * 16][tx * 4 + 3] = v.w;
    }
    __syncthreads();
    #pragma unroll
    for (int q = 0; q < 4; ++q) {
        int cl = ty + q * 16;
        ushort4 o;
        o.x = f2bf(tile[tx * 4 + 0][cl]);
        o.y = f2bf(tile[tx * 4 + 1][cl]);
        o.z = f2bf(tile[tx * 4 + 2][cl]);
        o.w = f2bf(tile[tx * 4 + 3][cl]);
        *(ushort4*)&dst[(c0 + cl) * R + r0 + tx * 4] = o;
    }
}

// ---------------------------------------------------------------------------
// GEMM1 (MFMA bf16): act = tanh(xb @ b1t^T + catBias), bf16 out
// 1-wave blocks, 32x32 tile, grid 32x24 = 768 blocks (3/CU).
// ---------------------------------------------------------------------------
__global__ __launch_bounds__(64) void k_gemm1(
    const ushort* __restrict__ xb, const ushort* __restrict__ b1t,
    const float* __restrict__ catBias, ushort* __restrict__ act)
{
    const int lane = threadIdx.x;
    const int n0 = blockIdx.x * 32;
    const int m0 = blockIdx.y * 32;
    const int lrow = lane & 15, lk = (lane >> 4) * 8;

    const ushort* pa0 = &xb[(m0 + lrow) * KD + lk];
    const ushort* pa1 = pa0 + 16 * KD;
    const ushort* pb0 = &b1t[(n0 + lrow) * KD + lk];
    const ushort* pb1 = pb0 + 16 * KD;

    f32x4 acc[2][2] = {};
    #pragma unroll 4
    for (int k0 = 0; k0 < KD; k0 += 32) {
        short8 a0 = *(const short8*)(pa0 + k0);
        short8 a1 = *(const short8*)(pa1 + k0);
        short8 b0 = *(const short8*)(pb0 + k0);
        short8 b1 = *(const short8*)(pb1 + k0);
        acc[0][0] = __builtin_amdgcn_mfma_f32_16x16x32_bf16(a0, b0, acc[0][0], 0, 0, 0);
        acc[0][1] = __builtin_amdgcn_mfma_f32_16x16x32_bf16(a0, b1, acc[0][1], 0, 0, 0);
        acc[1][0] = __builtin_amdgcn_mfma_f32_16x16x32_bf16(a1, b0, acc[1][0], 0, 0, 0);
        acc[1][1] = __builtin_amdgcn_mfma_f32_16x16x32_bf16(a1, b1, acc[1][1], 0, 0, 0);
    }
    const int crow = (lane >> 4) * 4, ccol = lane & 15;
    #pragma unroll
    for (int nf = 0; nf < 2; ++nf) {
        int col = n0 + nf * 16 + ccol;
        float cb = catBias[col];
        #pragma unroll
        for (int mf = 0; mf < 2; ++mf) {
            #pragma unroll
            for (int r = 0; r < 4; ++r) {
                int row = m0 + mf * 16 + crow + r;
                act[row * NC + col] = f2bf(fast_tanh(acc[mf][nf][r] + cb));
            }
        }
    }
}

// ---------------------------------------------------------------------------
// GEMM2 (MFMA bf16) + exp epilogue -> pw = EA | EM (f32).
// ---------------------------------------------------------------------------
__global__ __launch_bounds__(64) void k_gemm2(
    const ushort* __restrict__ act, const ushort* __restrict__ h2t,
    const float* __restrict__ hid2Bias, float* __restrict__ pw)
{
    const int lane = threadIdx.x;
    const int n0 = blockIdx.x * 32;
    const int m0 = blockIdx.y * 32;
    const bool top = (blockIdx.x < 16);
    const int koff = top ? 0 : 512;
    const int nc0  = top ? n0 : n0 - 512;
    const int lrow = lane & 15, lk = (lane >> 4) * 8;

    const ushort* pa0 = &act[(m0 + lrow) * NC + koff + lk];
    const ushort* pa1 = pa0 + 16 * NC;
    const ushort* pb0 = &h2t[(nc0 + lrow) * NC + koff + lk];
    const ushort* pb1 = pb0 + 16 * NC;

    f32x4 acc[2][2] = {};
    #pragma unroll 4
    for (int k0 = 0; k0 < KD; k0 += 32) {
        short8 a0 = *(const short8*)(pa0 + k0);
        short8 a1 = *(const short8*)(pa1 + k0);
        short8 b0 = *(const short8*)(pb0 + k0);
        short8 b1 = *(const short8*)(pb1 + k0);
        acc[0][0] = __builtin_amdgcn_mfma_f32_16x16x32_bf16(a0, b0, acc[0][0], 0, 0, 0);
        acc[0][1] = __builtin_amdgcn_mfma_f32_16x16x32_bf16(a0, b1, acc[0][1], 0, 0, 0);
        acc[1][0] = __builtin_amdgcn_mfma_f32_16x16x32_bf16(a1, b0, acc[1][0], 0, 0, 0);
        acc[1][1] = __builtin_amdgcn_mfma_f32_16x16x32_bf16(a1, b1, acc[1][1], 0, 0, 0);
    }
    const int crow = (lane >> 4) * 4, ccol = lane & 15;
    #pragma unroll
    for (int nf = 0; nf < 2; ++nf) {
        int col = n0 + nf * 16 + ccol;
        float hb = top ? hid2Bias[col] : 0.0f;
        #pragma unroll
        for (int mf = 0; mf < 2; ++mf) {
            #pragma unroll
            for (int r = 0; r < 4; ++r) {
                int row = m0 + mf * 16 + crow + r;
                pw[row * NC + col] = fast_exp2(RLN2_2 * (acc[mf][nf][r] + hb));
            }
        }
    }
}

// ---------------------------------------------------------------------------
// Pairwise: out[i][j] = (outBias + sum w) - 2*sum_h w[h]/(1 + EA[i,h]*EM[j,h])
// 32x16 tile / 4-wave block; wave wv covers h in [wv*128,+128).
// Micro 4i x 2j, packed f32x2 math (r12). w in LDS (r11: wave-private quarter,
// uniform broadcast reads) -> frees ~32 VGPR vs r12's register copy.
// __launch_bounds__(256,6): cap VGPR at ~85 -> 24 waves/CU (was 16 at VGPR=104).
// Wave-private staging, no main-loop barriers, 16-h chunks. Grid 1152 XCD-swz.
// ---------------------------------------------------------------------------
__global__ __launch_bounds__(256, 6) void k_pair(
    const float* __restrict__ pw, const float* __restrict__ w,
    const float* __restrict__ outBias, float* __restrict__ out)
{
    __shared__ float Ea[4][32][18];
    __shared__ float Em[4][16][18];
    __shared__ float wl[512];

    const int t    = threadIdx.x;
    const int wv   = t >> 6, lane = t & 63;
    const int bid  = blockIdx.x;
    const int sw   = (bid & 7) * 144 + (bid >> 3);   // XCD swizzle (8 | 1152)
    const int it = sw / 48, jt = sw % 48;            // 24 x 48 tiles
    const int i0 = it * 32, j0 = jt * 16;
    const int hb0 = wv * 128;                        // this wave's h-quarter

    // w: each wave stages its own h-quarter into wl (reads only own quarter,
    // ordered behind own writes). lsum over full 512 via global + butterfly.
    *(float2*)&wl[hb0 + lane * 2] = *(const float2*)&w[hb0 + lane * 2];
    float4 wa = *(const float4*)&w[lane * 8];
    float4 wb = *(const float4*)&w[lane * 8 + 4];
    float lsum = (wa.x + wa.y) + (wa.z + wa.w) + (wb.x + wb.y) + (wb.z + wb.w);
    #pragma unroll
    for (int d = 1; d < 64; d <<= 1) lsum += __shfl_xor(lsum, d, 64);

    // staging geometry (per-chunk: Ea 32x16, Em 16x16)
    const int sra = lane >> 1;            // 0..31
    const int sca = (lane & 1) * 8;       // 0 or 8
    const int srm = lane >> 2;            // 0..15
    const int scm = (lane & 3) * 4;       // 1 float4
    const float* srcA = &pw[(i0 + sra) * NC + hb0 + sca];
    const float* srcM = &pw[(j0 + srm) * NC + 512 + hb0 + scm];

    // compute geometry: lane = (li, lj) 8x8; rows 4li..4li+3, cols 2lj,2lj+1
    const int li = lane >> 3, lj = lane & 7;

    float4 fa0 = *(const float4*)(srcA);
    float4 fa1 = *(const float4*)(srcA + 4);
    float4 fm  = *(const float4*)(srcM);

    const f32x2 one2 = {1.0f, 1.0f};
    f32x2 acc0[2] = {}, acc1[2] = {}, acc2[2] = {}, acc3[2] = {};

    #pragma unroll 1
    for (int c = 0; c < 8; ++c) {                    // 8 chunks x 16 h
        const int hh = c * 16;
        // stage (wave-private; DS pipe in-order per wave)
        *(float4*)&Ea[wv][sra][sca]     = fa0;
        *(float4*)&Ea[wv][sra][sca + 4] = fa1;
        *(float4*)&Em[wv][srm][scm]     = fm;
        if (c < 7) {
            fa0 = *(const float4*)(srcA + hh + 16);
            fa1 = *(const float4*)(srcA + hh + 20);
            fm  = *(const float4*)(srcM + hh + 16);
        }
        #pragma unroll
        for (int hq = 0; hq < 4; ++hq) {
            float4 e0 = *(const float4*)&Ea[wv][4 * li + 0][hq * 4];
            float4 e1 = *(const float4*)&Ea[wv][4 * li + 1][hq * 4];
            float4 e2 = *(const float4*)&Ea[wv][4 * li + 2][hq * 4];
            float4 e3 = *(const float4*)&Ea[wv][4 * li + 3][hq * 4];
            float4 f0 = *(const float4*)&Em[wv][2 * lj    ][hq * 4];
            float4 f1 = *(const float4*)&Em[wv][2 * lj + 1][hq * 4];
            float4 w4 = *(const float4*)&wl[hb0 + hh + hq * 4];  // broadcast
            #define PKQUAD(DA, DB, WH, ACCA, ACCB)                           \
            {                                                                \
                f32x2 Q  = DA * DB;                                          \
                float pr = Q.x * Q.y;                                        \
                float R  = fast_rcp(pr);                                     \
                float RW = R * (WH);                                         \
                f32x2 T  = (f32x2){Q.y, Q.x} * RW;                           \
                ACCA = __builtin_elementwise_fma(T, DB, ACCA);               \
                ACCB = __builtin_elementwise_fma(T, DA, ACCB);               \
            }
            #define HSTEP(H, S)                                                        \
            {                                                                          \
                f32x2 F  = {f0.H, f1.H};                                               \
                f32x2 D0 = __builtin_elementwise_fma((f32x2){e0.H, e0.H}, F, one2);    \
                f32x2 D1 = __builtin_elementwise_fma((f32x2){e1.H, e1.H}, F, one2);    \
                f32x2 D2 = __builtin_elementwise_fma((f32x2){e2.H, e2.H}, F, one2);    \
                f32x2 D3 = __builtin_elementwise_fma((f32x2){e3.H, e3.H}, F, one2);    \
                PKQUAD(D0, D1, w4.H, acc0[S], acc1[S])                                 \
                PKQUAD(D2, D3, w4.H, acc2[S], acc3[S])                                 \
            }
            HSTEP(x, 0) HSTEP(y, 1) HSTEP(z, 0) HSTEP(w, 1)
            #undef HSTEP
            #undef PKQUAD
        }
    }

    f32x2 s0 = acc0[0] + acc0[1];
    f32x2 s1 = acc1[0] + acc1[1];
    f32x2 s2 = acc2[0] + acc2[1];
    f32x2 s3 = acc3[0] + acc3[1];

    // combine 4 h-quarters: waves 1..3 park 8 partials each in LDS overlay
    // on Ea (1536 floats <= 2304), wave 0 sums and writes out.
    float* partial = (float*)Ea;
    __syncthreads();
    if (wv >= 1) {
        float* p = partial + (wv - 1) * 512 + lane * 8;
        p[0] = s0.x; p[1] = s0.y; p[2] = s1.x; p[3] = s1.y;
        p[4] = s2.x; p[5] = s2.y; p[6] = s3.x; p[7] = s3.y;
    }
    __syncthreads();
    if (wv == 0) {
        const float base = lsum + outBias[0];
        float tt[8] = {s0.x, s0.y, s1.x, s1.y, s2.x, s2.y, s3.x, s3.y};
        #pragma unroll
        for (int q = 0; q < 3; ++q) {
            const float* p = partial + q * 512 + lane * 8;
            #pragma unroll
            for (int k = 0; k < 8; ++k) tt[k] += p[k];
        }
        const int gj = j0 + 2 * lj;
        #pragma unroll
        for (int r = 0; r < 4; ++r) {
            const int gi = i0 + 4 * li + r;
            float2 o;
            o.x = fmaf(-2.f, tt[2 * r],     base);
            o.y = fmaf(-2.f, tt[2 * r + 1], base);
            *(float2*)&out[gi * TT + gj] = o;
        }
    }
}

extern "C" void kernel_launch(void* const* d_in, const int* in_sizes, int n_in,
                              void* d_out, int out_size, void* d_ws, size_t ws_size,
                              hipStream_t stream) {
    const float* x        = (const float*)d_in[0];
    const float* foh      = (const float*)d_in[1];
    const float* fom      = (const float*)d_in[2];
    const float* catBias  = (const float*)d_in[3];
    const float* hid2     = (const float*)d_in[4];
    const float* hid2Bias = (const float*)d_in[5];
    const float* outLayer = (const float*)d_in[6];
    const float* outBias  = (const float*)d_in[7];
    float* out = (float*)d_out;

    char* wsb = (char*)d_ws;
    float*  pw  = (float*)(wsb);                        // 768*1024*4
    ushort* act = (ushort*)(wsb + 3145728);             // 768*1024*2
    ushort* xb  = (ushort*)(wsb + 4718592);             // 768*512*2
    ushort* b1t = (ushort*)(wsb + 5505024);             // 1024*512*2
    ushort* h2t = (ushort*)(wsb + 6553600);             // 512*1024*2

    k_prep <<<dim3(352),    256, 0, stream>>>(x, foh, fom, hid2, xb, b1t, h2t);
    k_gemm1<<<dim3(32, 24),  64, 0, stream>>>(xb, b1t, catBias, act);
    k_gemm2<<<dim3(32, 24),  64, 0, stream>>>(act, h2t, hid2Bias, pw);
    k_pair <<<dim3(1152),   256, 0, stream>>>(pw, outLayer, outBias, out);
}

// Round 14
// 61.073 us; speedup vs baseline: 1.1123x; 1.1123x over previous
//
#include <hip/hip_runtime.h>

#define TT 768
#define KD 512
#define NC 1024
#define RLN2_2 2.8853900817779268f   // 2/ln(2)

typedef short short8 __attribute__((ext_vector_type(8)));
typedef float f32x4  __attribute__((ext_vector_type(4)));
typedef float f32x2  __attribute__((ext_vector_type(2)));

__device__ __forceinline__ float fast_exp2(float x) {
#if __has_builtin(__builtin_amdgcn_exp2f)
    return __builtin_amdgcn_exp2f(x);
#else
    return exp2f(x);
#endif
}
__device__ __forceinline__ float fast_rcp(float x) {
#if __has_builtin(__builtin_amdgcn_rcpf)
    return __builtin_amdgcn_rcpf(x);
#else
    return 1.0f / x;
#endif
}
__device__ __forceinline__ float fast_tanh(float x) {
    float e = fast_exp2(x * RLN2_2);
    return fmaf(-2.0f, fast_rcp(e + 1.0f), 1.0f);
}
__device__ __forceinline__ ushort f2bf(float f) {   // RNE f32->bf16
    uint u = __float_as_uint(f);
    u += 0x7fff + ((u >> 16) & 1);
    return (ushort)(u >> 16);
}

// ---------------------------------------------------------------------------
// Prep: x->bf16; foh/fom -> [c][k] bf16; hid2 -> [n][k] bf16 (transposes)
// ---------------------------------------------------------------------------
__global__ __launch_bounds__(256) void k_prep(
    const float* __restrict__ x, const float* __restrict__ foh,
    const float* __restrict__ fom, const float* __restrict__ hid2,
    ushort* __restrict__ xb, ushort* __restrict__ b1t, ushort* __restrict__ h2t)
{
    const int b = blockIdx.x, t = threadIdx.x;
    if (b < 96) {
        int base = b * 4096 + t * 16;
        #pragma unroll
        for (int q = 0; q < 4; ++q) {
            float4 v = *(const float4*)&x[base + q * 4];
            ushort4 o; o.x = f2bf(v.x); o.y = f2bf(v.y); o.z = f2bf(v.z); o.w = f2bf(v.w);
            *(ushort4*)&xb[base + q * 4] = o;
        }
        return;
    }
    __shared__ float tile[64][65];
    const float* src; ushort* dst; int R, C, r0, c0;
    if (b < 160)      { int bb = b - 96;  src = foh;  dst = b1t;             R = 512;  C = 512; r0 = (bb >> 3) * 64; c0 = (bb & 7) * 64; }
    else if (b < 224) { int bb = b - 160; src = fom;  dst = b1t + 512 * 512; R = 512;  C = 512; r0 = (bb >> 3) * 64; c0 = (bb & 7) * 64; }
    else              { int bb = b - 224; src = hid2; dst = h2t;             R = 1024; C = 512; r0 = (bb >> 3) * 64; c0 = (bb & 7) * 64; }
    const int ty = t >> 4, tx = t & 15;
    #pragma unroll
    for (int q = 0; q < 4; ++q) {
        float4 v = *(const float4*)&src[(r0 + ty + q * 16) * C + c0 + tx * 4];
        tile[ty + q * 16][tx * 4 + 0] = v.x;
        tile[ty + q * 16][tx * 4 + 1] = v.y;
        tile[ty + q * 16][tx * 4 + 2] = v.z;
        tile[ty + q * 16][tx * 4 + 3] = v.w;
    }
    __syncthreads();
    #pragma unroll
    for (int q = 0; q < 4; ++q) {
        int cl = ty + q * 16;
        ushort4 o;
        o.x = f2bf(tile[tx * 4 + 0][cl]);
        o.y = f2bf(tile[tx * 4 + 1][cl]);
        o.z = f2bf(tile[tx * 4 + 2][cl]);
        o.w = f2bf(tile[tx * 4 + 3][cl]);
        *(ushort4*)&dst[(c0 + cl) * R + r0 + tx * 4] = o;
    }
}

// ---------------------------------------------------------------------------
// GEMM1 (MFMA bf16): act = tanh(xb @ b1t^T + catBias), bf16 out
// 1-wave blocks, 32x32 tile, grid 32x24 = 768 blocks (3/CU).
// ---------------------------------------------------------------------------
__global__ __launch_bounds__(64) void k_gemm1(
    const ushort* __restrict__ xb, const ushort* __restrict__ b1t,
    const float* __restrict__ catBias, ushort* __restrict__ act)
{
    const int lane = threadIdx.x;
    const int n0 = blockIdx.x * 32;
    const int m0 = blockIdx.y * 32;
    const int lrow = lane & 15, lk = (lane >> 4) * 8;

    const ushort* pa0 = &xb[(m0 + lrow) * KD + lk];
    const ushort* pa1 = pa0 + 16 * KD;
    const ushort* pb0 = &b1t[(n0 + lrow) * KD + lk];
    const ushort* pb1 = pb0 + 16 * KD;

    f32x4 acc[2][2] = {};
    #pragma unroll 4
    for (int k0 = 0; k0 < KD; k0 += 32) {
        short8 a0 = *(const short8*)(pa0 + k0);
        short8 a1 = *(const short8*)(pa1 + k0);
        short8 b0 = *(const short8*)(pb0 + k0);
        short8 b1 = *(const short8*)(pb1 + k0);
        acc[0][0] = __builtin_amdgcn_mfma_f32_16x16x32_bf16(a0, b0, acc[0][0], 0, 0, 0);
        acc[0][1] = __builtin_amdgcn_mfma_f32_16x16x32_bf16(a0, b1, acc[0][1], 0, 0, 0);
        acc[1][0] = __builtin_amdgcn_mfma_f32_16x16x32_bf16(a1, b0, acc[1][0], 0, 0, 0);
        acc[1][1] = __builtin_amdgcn_mfma_f32_16x16x32_bf16(a1, b1, acc[1][1], 0, 0, 0);
    }
    const int crow = (lane >> 4) * 4, ccol = lane & 15;
    #pragma unroll
    for (int nf = 0; nf < 2; ++nf) {
        int col = n0 + nf * 16 + ccol;
        float cb = catBias[col];
        #pragma unroll
        for (int mf = 0; mf < 2; ++mf) {
            #pragma unroll
            for (int r = 0; r < 4; ++r) {
                int row = m0 + mf * 16 + crow + r;
                act[row * NC + col] = f2bf(fast_tanh(acc[mf][nf][r] + cb));
            }
        }
    }
}

// ---------------------------------------------------------------------------
// GEMM2 (MFMA bf16) + exp epilogue -> pw = EA | EM (f32).
// ---------------------------------------------------------------------------
__global__ __launch_bounds__(64) void k_gemm2(
    const ushort* __restrict__ act, const ushort* __restrict__ h2t,
    const float* __restrict__ hid2Bias, float* __restrict__ pw)
{
    const int lane = threadIdx.x;
    const int n0 = blockIdx.x * 32;
    const int m0 = blockIdx.y * 32;
    const bool top = (blockIdx.x < 16);
    const int koff = top ? 0 : 512;
    const int nc0  = top ? n0 : n0 - 512;
    const int lrow = lane & 15, lk = (lane >> 4) * 8;

    const ushort* pa0 = &act[(m0 + lrow) * NC + koff + lk];
    const ushort* pa1 = pa0 + 16 * NC;
    const ushort* pb0 = &h2t[(nc0 + lrow) * NC + koff + lk];
    const ushort* pb1 = pb0 + 16 * NC;

    f32x4 acc[2][2] = {};
    #pragma unroll 4
    for (int k0 = 0; k0 < KD; k0 += 32) {
        short8 a0 = *(const short8*)(pa0 + k0);
        short8 a1 = *(const short8*)(pa1 + k0);
        short8 b0 = *(const short8*)(pb0 + k0);
        short8 b1 = *(const short8*)(pb1 + k0);
        acc[0][0] = __builtin_amdgcn_mfma_f32_16x16x32_bf16(a0, b0, acc[0][0], 0, 0, 0);
        acc[0][1] = __builtin_amdgcn_mfma_f32_16x16x32_bf16(a0, b1, acc[0][1], 0, 0, 0);
        acc[1][0] = __builtin_amdgcn_mfma_f32_16x16x32_bf16(a1, b0, acc[1][0], 0, 0, 0);
        acc[1][1] = __builtin_amdgcn_mfma_f32_16x16x32_bf16(a1, b1, acc[1][1], 0, 0, 0);
    }
    const int crow = (lane >> 4) * 4, ccol = lane & 15;
    #pragma unroll
    for (int nf = 0; nf < 2; ++nf) {
        int col = n0 + nf * 16 + ccol;
        float hb = top ? hid2Bias[col] : 0.0f;
        #pragma unroll
        for (int mf = 0; mf < 2; ++mf) {
            #pragma unroll
            for (int r = 0; r < 4; ++r) {
                int row = m0 + mf * 16 + crow + r;
                pw[row * NC + col] = fast_exp2(RLN2_2 * (acc[mf][nf][r] + hb));
            }
        }
    }
}

// ---------------------------------------------------------------------------
// Pairwise: out[i][j] = (outBias + sum w) - 2*sum_h w[h]/(1 + EA[i,h]*EM[j,h])
// r11 geometry (16x16 tile / 4-wave h-split / wave-private staging / no main-
// loop barriers / grid 2304 XCD-swz) + r12 packed f32x2 math + w in LDS.
// Micro 2i x 2j -> low register pressure (target VGPR <= 64 for 8 waves/SIMD,
// 32 waves/CU resident). NO launch_bounds cap (r13's spill lesson).
// LDS 11264 B.
// ---------------------------------------------------------------------------
__global__ __launch_bounds__(256) void k_pair(
    const float* __restrict__ pw, const float* __restrict__ w,
    const float* __restrict__ outBias, float* __restrict__ out)
{
    __shared__ float Ea[4][16][18];
    __shared__ float Em[4][16][18];
    __shared__ float wl[512];

    const int t    = threadIdx.x;
    const int wv   = t >> 6, lane = t & 63;
    const int bid  = blockIdx.x;
    const int sw   = (bid & 7) * 288 + (bid >> 3);   // XCD swizzle (8 | 2304)
    const int it = sw / 48, jt = sw % 48;
    const int i0 = it * 16, j0 = jt * 16;
    const int hb0 = wv * 128;                        // this wave's h-quarter

    // w: each wave stages its own h-quarter into wl (reads only own quarter,
    // ordered behind its own writes). lsum over full 512 via global+butterfly.
    *(float2*)&wl[hb0 + lane * 2] = *(const float2*)&w[hb0 + lane * 2];
    {
        float4 wa = *(const float4*)&w[lane * 8];
        float4 wb = *(const float4*)&w[lane * 8 + 4];
        float ls = (wa.x + wa.y) + (wa.z + wa.w) + (wb.x + wb.y) + (wb.z + wb.w);
        #pragma unroll
        for (int d = 1; d < 64; d <<= 1) ls += __shfl_xor(ls, d, 64);
        // stash in a single reg
        wl[0] = wl[0];  // no-op to keep ordering trivial
        // keep ls in scope below
        // (fallthrough)
        __asm__ volatile("" ::: );
        // store to stack-free var:
        // use a local:
        // handled below via lsum variable
        // -- we simply assign:
        // (see lsum declaration)
        // NOTE: restructured: lsum declared here
        #define LSUM_READY ls
        {
            const float lsum = LSUM_READY;

            // staging geometry: 16 rows x 16 cols per chunk; 1 float4 / lane
            const int sr = lane >> 2;            // 0..15
            const int sc = (lane & 3) * 4;       // 0..12
            const float* srcA = &pw[(i0 + sr) * NC + hb0 + sc];
            const float* srcM = &pw[(j0 + sr) * NC + 512 + hb0 + sc];

            // compute geometry: lane = (li, lj) 8x8
            const int li = lane >> 3, lj = lane & 7;

            float4 fa = *(const float4*)(srcA);
            float4 fm = *(const float4*)(srcM);

            const f32x2 one2 = {1.0f, 1.0f};
            f32x2 accA[2] = {}, accB[2] = {};    // rows 2li / 2li+1, slots 0/1

            #pragma unroll 1
            for (int c = 0; c < 8; ++c) {        // 8 chunks x 16 h
                const int hh = c * 16;
                *(float4*)&Ea[wv][sr][sc] = fa;  // wave-private; in-order DS
                *(float4*)&Em[wv][sr][sc] = fm;
                if (c < 7) {
                    fa = *(const float4*)(srcA + hh + 16);
                    fm = *(const float4*)(srcM + hh + 16);
                }
                #pragma unroll
                for (int hq = 0; hq < 4; ++hq) {
                    float4 e0 = *(const float4*)&Ea[wv][2 * li    ][hq * 4];
                    float4 e1 = *(const float4*)&Ea[wv][2 * li + 1][hq * 4];
                    float4 f0 = *(const float4*)&Em[wv][2 * lj    ][hq * 4];
                    float4 f1 = *(const float4*)&Em[wv][2 * lj + 1][hq * 4];
                    float4 w4 = *(const float4*)&wl[hb0 + hh + hq * 4]; // bcast
                    #define PKQUAD(DA, DB, WH, ACCA, ACCB)                   \
                    {                                                        \
                        f32x2 Q  = DA * DB;                                  \
                        float pr = Q.x * Q.y;                                \
                        float R  = fast_rcp(pr);                             \
                        float RW = R * (WH);                                 \
                        f32x2 T  = (f32x2){Q.y, Q.x} * RW;                   \
                        ACCA = __builtin_elementwise_fma(T, DB, ACCA);       \
                        ACCB = __builtin_elementwise_fma(T, DA, ACCB);       \
                    }
                    #define HSTEP(H, S)                                                     \
                    {                                                                       \
                        f32x2 F  = {f0.H, f1.H};                                            \
                        f32x2 D0 = __builtin_elementwise_fma((f32x2){e0.H, e0.H}, F, one2); \
                        f32x2 D1 = __builtin_elementwise_fma((f32x2){e1.H, e1.H}, F, one2); \
                        PKQUAD(D0, D1, w4.H, accA[S], accB[S])                              \
                    }
                    HSTEP(x, 0) HSTEP(y, 1) HSTEP(z, 0) HSTEP(w, 1)
                    #undef HSTEP
                    #undef PKQUAD
                }
            }

            f32x2 s0 = accA[0] + accA[1];        // row 2li:   (j0, j1)
            f32x2 s1 = accB[0] + accB[1];        // row 2li+1: (j0, j1)

            // combine 4 h-quarters: waves 1..3 park partials in LDS overlay
            // on Ea (768 floats <= 1152), wave 0 sums and writes out.
            float* partial = (float*)Ea;
            __syncthreads();
            if (wv >= 1) {
                float* p = partial + (wv - 1) * 256 + lane * 4;
                p[0] = s0.x; p[1] = s0.y; p[2] = s1.x; p[3] = s1.y;
            }
            __syncthreads();
            if (wv == 0) {
                const float base = lsum + outBias[0];
                float t00 = s0.x, t01 = s0.y, t10 = s1.x, t11 = s1.y;
                #pragma unroll
                for (int q = 0; q < 3; ++q) {
                    const float* p = partial + q * 256 + lane * 4;
                    t00 += p[0]; t01 += p[1]; t10 += p[2]; t11 += p[3];
                }
                const int gi = i0 + 2 * li, gj = j0 + 2 * lj;
                float2 o0, o1;
                o0.x = fmaf(-2.f, t00, base);
                o0.y = fmaf(-2.f, t01, base);
                o1.x = fmaf(-2.f, t10, base);
                o1.y = fmaf(-2.f, t11, base);
                *(float2*)&out[gi * TT + gj]       = o0;
                *(float2*)&out[(gi + 1) * TT + gj] = o1;
            }
        }
        #undef LSUM_READY
    }
}

extern "C" void kernel_launch(void* const* d_in, const int* in_sizes, int n_in,
                              void* d_out, int out_size, void* d_ws, size_t ws_size,
                              hipStream_t stream) {
    const float* x        = (const float*)d_in[0];
    const float* foh      = (const float*)d_in[1];
    const float* fom      = (const float*)d_in[2];
    const float* catBias  = (const float*)d_in[3];
    const float* hid2     = (const float*)d_in[4];
    const float* hid2Bias = (const float*)d_in[5];
    const float* outLayer = (const float*)d_in[6];
    const float* outBias  = (const float*)d_in[7];
    float* out = (float*)d_out;

    char* wsb = (char*)d_ws;
    float*  pw  = (float*)(wsb);                        // 768*1024*4
    ushort* act = (ushort*)(wsb + 3145728);             // 768*1024*2
    ushort* xb  = (ushort*)(wsb + 4718592);             // 768*512*2
    ushort* b1t = (ushort*)(wsb + 5505024);             // 1024*512*2
    ushort* h2t = (ushort*)(wsb + 6553600);             // 512*1024*2

    k_prep <<<dim3(352),    256, 0, stream>>>(x, foh, fom, hid2, xb, b1t, h2t);
    k_gemm1<<<dim3(32, 24),  64, 0, stream>>>(xb, b1t, catBias, act);
    k_gemm2<<<dim3(32, 24),  64, 0, stream>>>(act, h2t, hid2Bias, pw);
    k_pair <<<dim3(2304),   256, 0, stream>>>(pw, outLayer, outBias, out);
}

// Round 15
// 58.843 us; speedup vs baseline: 1.1545x; 1.0379x over previous
//
#include <hip/hip_runtime.h>

#define TT 768
#define KD 512
#define NC 1024
#define RLN2_2 2.8853900817779268f   // 2/ln(2)

typedef short short8 __attribute__((ext_vector_type(8)));
typedef float f32x4  __attribute__((ext_vector_type(4)));
typedef float f32x2  __attribute__((ext_vector_type(2)));

__device__ __forceinline__ float fast_exp2(float x) {
#if __has_builtin(__builtin_amdgcn_exp2f)
    return __builtin_amdgcn_exp2f(x);
#else
    return exp2f(x);
#endif
}
__device__ __forceinline__ float fast_rcp(float x) {
#if __has_builtin(__builtin_amdgcn_rcpf)
    return __builtin_amdgcn_rcpf(x);
#else
    return 1.0f / x;
#endif
}
__device__ __forceinline__ float fast_tanh(float x) {
    float e = fast_exp2(x * RLN2_2);
    return fmaf(-2.0f, fast_rcp(e + 1.0f), 1.0f);
}
__device__ __forceinline__ ushort f2bf(float f) {   // RNE f32->bf16
    uint u = __float_as_uint(f);
    u += 0x7fff + ((u >> 16) & 1);
    return (ushort)(u >> 16);
}

// ---------------------------------------------------------------------------
// Prep: x->bf16 (blocks 0..383); transposes in 32x32 tiles, 64-thr blocks
// (blocks 384..1407): foh/fom -> b1t [c][k] bf16; hid2 -> h2t [n][k] bf16.
// 1408 blocks = 5.5/CU (was 1.4/CU) for latency hiding.
// ---------------------------------------------------------------------------
__global__ __launch_bounds__(64) void k_prep(
    const float* __restrict__ x, const float* __restrict__ foh,
    const float* __restrict__ fom, const float* __restrict__ hid2,
    ushort* __restrict__ xb, ushort* __restrict__ b1t, ushort* __restrict__ h2t)
{
    const int b = blockIdx.x, lane = threadIdx.x;
    if (b < 384) {
        int base = b * 1024 + lane * 16;
        #pragma unroll
        for (int q = 0; q < 4; ++q) {
            float4 v = *(const float4*)&x[base + q * 4];
            ushort4 o; o.x = f2bf(v.x); o.y = f2bf(v.y); o.z = f2bf(v.z); o.w = f2bf(v.w);
            *(ushort4*)&xb[base + q * 4] = o;
        }
        return;
    }
    __shared__ float tile[32][33];
    int bb = b - 384;
    const float* src; ushort* dst; int R, C;
    if (bb < 256)      { src = foh;  dst = b1t;             R = 512;  C = 512; }
    else if (bb < 512) { src = fom;  dst = b1t + 512 * 512; R = 512;  C = 512; bb -= 256; }
    else               { src = hid2; dst = h2t;             R = 1024; C = 512; bb -= 512; }
    const int r0 = (bb >> 4) * 32, c0 = (bb & 15) * 32;
    const int ty = lane >> 3, tx = lane & 7;
    #pragma unroll
    for (int q = 0; q < 4; ++q) {
        float4 v = *(const float4*)&src[(r0 + ty + q * 8) * C + c0 + tx * 4];
        tile[ty + q * 8][tx * 4 + 0] = v.x;
        tile[ty + q * 8][tx * 4 + 1] = v.y;
        tile[ty + q * 8][tx * 4 + 2] = v.z;
        tile[ty + q * 8][tx * 4 + 3] = v.w;
    }
    __syncthreads();
    #pragma unroll
    for (int q = 0; q < 4; ++q) {
        int cl = ty + q * 8;
        ushort4 o;
        o.x = f2bf(tile[tx * 4 + 0][cl]);
        o.y = f2bf(tile[tx * 4 + 1][cl]);
        o.z = f2bf(tile[tx * 4 + 2][cl]);
        o.w = f2bf(tile[tx * 4 + 3][cl]);
        *(ushort4*)&dst[(c0 + cl) * R + r0 + tx * 4] = o;
    }
}

// ---------------------------------------------------------------------------
// GEMM1 (MFMA bf16) with 2-wave K-SPLIT: wave kv sums k in [kv*256, +256).
// 32x32 tile, grid 32x24 = 768 blocks x 128 thr = 6 waves/CU (was 3).
// Wave 1 parks acc in LDS; wave 0 combines + tanh epilogue.
// ---------------------------------------------------------------------------
__global__ __launch_bounds__(128) void k_gemm1(
    const ushort* __restrict__ xb, const ushort* __restrict__ b1t,
    const float* __restrict__ catBias, ushort* __restrict__ act)
{
    __shared__ float ps[64][20];
    const int t = threadIdx.x;
    const int kv = t >> 6, lane = t & 63;
    const int n0 = blockIdx.x * 32;
    const int m0 = blockIdx.y * 32;
    const int lrow = lane & 15, lk = (lane >> 4) * 8;
    const int kbase = kv * 256;

    const ushort* pa0 = &xb[(m0 + lrow) * KD + kbase + lk];
    const ushort* pa1 = pa0 + 16 * KD;
    const ushort* pb0 = &b1t[(n0 + lrow) * KD + kbase + lk];
    const ushort* pb1 = pb0 + 16 * KD;

    f32x4 acc[2][2] = {};
    #pragma unroll 4
    for (int k0 = 0; k0 < 256; k0 += 32) {
        short8 a0 = *(const short8*)(pa0 + k0);
        short8 a1 = *(const short8*)(pa1 + k0);
        short8 b0 = *(const short8*)(pb0 + k0);
        short8 b1 = *(const short8*)(pb1 + k0);
        acc[0][0] = __builtin_amdgcn_mfma_f32_16x16x32_bf16(a0, b0, acc[0][0], 0, 0, 0);
        acc[0][1] = __builtin_amdgcn_mfma_f32_16x16x32_bf16(a0, b1, acc[0][1], 0, 0, 0);
        acc[1][0] = __builtin_amdgcn_mfma_f32_16x16x32_bf16(a1, b0, acc[1][0], 0, 0, 0);
        acc[1][1] = __builtin_amdgcn_mfma_f32_16x16x32_bf16(a1, b1, acc[1][1], 0, 0, 0);
    }
    if (kv == 1) {
        *(f32x4*)&ps[lane][0]  = acc[0][0];
        *(f32x4*)&ps[lane][4]  = acc[0][1];
        *(f32x4*)&ps[lane][8]  = acc[1][0];
        *(f32x4*)&ps[lane][12] = acc[1][1];
    }
    __syncthreads();
    if (kv == 0) {
        acc[0][0] += *(const f32x4*)&ps[lane][0];
        acc[0][1] += *(const f32x4*)&ps[lane][4];
        acc[1][0] += *(const f32x4*)&ps[lane][8];
        acc[1][1] += *(const f32x4*)&ps[lane][12];
        const int crow = (lane >> 4) * 4, ccol = lane & 15;
        #pragma unroll
        for (int nf = 0; nf < 2; ++nf) {
            int col = n0 + nf * 16 + ccol;
            float cb = catBias[col];
            #pragma unroll
            for (int mf = 0; mf < 2; ++mf) {
                #pragma unroll
                for (int r = 0; r < 4; ++r) {
                    int row = m0 + mf * 16 + crow + r;
                    act[row * NC + col] = f2bf(fast_tanh(acc[mf][nf][r] + cb));
                }
            }
        }
    }
}

// ---------------------------------------------------------------------------
// GEMM2 (MFMA bf16) + exp epilogue -> pw = EA | EM (f32). Same K-split.
// ---------------------------------------------------------------------------
__global__ __launch_bounds__(128) void k_gemm2(
    const ushort* __restrict__ act, const ushort* __restrict__ h2t,
    const float* __restrict__ hid2Bias, float* __restrict__ pw)
{
    __shared__ float ps[64][20];
    const int t = threadIdx.x;
    const int kv = t >> 6, lane = t & 63;
    const int n0 = blockIdx.x * 32;
    const int m0 = blockIdx.y * 32;
    const bool top = (blockIdx.x < 16);
    const int koff = top ? 0 : 512;
    const int nc0  = top ? n0 : n0 - 512;
    const int lrow = lane & 15, lk = (lane >> 4) * 8;
    const int kbase = kv * 256;

    const ushort* pa0 = &act[(m0 + lrow) * NC + koff + kbase + lk];
    const ushort* pa1 = pa0 + 16 * NC;
    const ushort* pb0 = &h2t[(nc0 + lrow) * NC + koff + kbase + lk];
    const ushort* pb1 = pb0 + 16 * NC;

    f32x4 acc[2][2] = {};
    #pragma unroll 4
    for (int k0 = 0; k0 < 256; k0 += 32) {
        short8 a0 = *(const short8*)(pa0 + k0);
        short8 a1 = *(const short8*)(pa1 + k0);
        short8 b0 = *(const short8*)(pb0 + k0);
        short8 b1 = *(const short8*)(pb1 + k0);
        acc[0][0] = __builtin_amdgcn_mfma_f32_16x16x32_bf16(a0, b0, acc[0][0], 0, 0, 0);
        acc[0][1] = __builtin_amdgcn_mfma_f32_16x16x32_bf16(a0, b1, acc[0][1], 0, 0, 0);
        acc[1][0] = __builtin_amdgcn_mfma_f32_16x16x32_bf16(a1, b0, acc[1][0], 0, 0, 0);
        acc[1][1] = __builtin_amdgcn_mfma_f32_16x16x32_bf16(a1, b1, acc[1][1], 0, 0, 0);
    }
    if (kv == 1) {
        *(f32x4*)&ps[lane][0]  = acc[0][0];
        *(f32x4*)&ps[lane][4]  = acc[0][1];
        *(f32x4*)&ps[lane][8]  = acc[1][0];
        *(f32x4*)&ps[lane][12] = acc[1][1];
    }
    __syncthreads();
    if (kv == 0) {
        acc[0][0] += *(const f32x4*)&ps[lane][0];
        acc[0][1] += *(const f32x4*)&ps[lane][4];
        acc[1][0] += *(const f32x4*)&ps[lane][8];
        acc[1][1] += *(const f32x4*)&ps[lane][12];
        const int crow = (lane >> 4) * 4, ccol = lane & 15;
        #pragma unroll
        for (int nf = 0; nf < 2; ++nf) {
            int col = n0 + nf * 16 + ccol;
            float hb = top ? hid2Bias[col] : 0.0f;
            #pragma unroll
            for (int mf = 0; mf < 2; ++mf) {
                #pragma unroll
                for (int r = 0; r < 4; ++r) {
                    int row = m0 + mf * 16 + crow + r;
                    pw[row * NC + col] = fast_exp2(RLN2_2 * (acc[mf][nf][r] + hb));
                }
            }
        }
    }
}

// ---------------------------------------------------------------------------
// Pairwise: out[i][j] = (outBias + sum w) - 2*sum_h w[h]/(1 + EA[i,h]*EM[j,h])
// [FROZEN = r14, cleaned]: 16x16 tile / 4-wave h-split (h in [wv*128,+128)) /
// wave-private staging / no main-loop barriers / packed f32x2 math / w in LDS.
// Grid 2304 XCD-swz x 4 waves; VGPR <= 64 -> 32 waves/CU resident.
// ---------------------------------------------------------------------------
__global__ __launch_bounds__(256) void k_pair(
    const float* __restrict__ pw, const float* __restrict__ w,
    const float* __restrict__ outBias, float* __restrict__ out)
{
    __shared__ float Ea[4][16][18];
    __shared__ float Em[4][16][18];
    __shared__ float wl[512];

    const int t    = threadIdx.x;
    const int wv   = t >> 6, lane = t & 63;
    const int bid  = blockIdx.x;
    const int sw   = (bid & 7) * 288 + (bid >> 3);   // XCD swizzle (8 | 2304)
    const int it = sw / 48, jt = sw % 48;
    const int i0 = it * 16, j0 = jt * 16;
    const int hb0 = wv * 128;                        // this wave's h-quarter

    // w: each wave stages its own h-quarter into wl (reads only own quarter,
    // ordered behind its own writes). lsum over full 512 via global+butterfly.
    *(float2*)&wl[hb0 + lane * 2] = *(const float2*)&w[hb0 + lane * 2];
    float4 wa = *(const float4*)&w[lane * 8];
    float4 wb = *(const float4*)&w[lane * 8 + 4];
    float lsum = (wa.x + wa.y) + (wa.z + wa.w) + (wb.x + wb.y) + (wb.z + wb.w);
    #pragma unroll
    for (int d = 1; d < 64; d <<= 1) lsum += __shfl_xor(lsum, d, 64);

    // staging geometry: 16 rows x 16 cols per chunk; 1 float4 / lane / array
    const int sr = lane >> 2;            // 0..15
    const int sc = (lane & 3) * 4;       // 0..12
    const float* srcA = &pw[(i0 + sr) * NC + hb0 + sc];
    const float* srcM = &pw[(j0 + sr) * NC + 512 + hb0 + sc];

    // compute geometry: lane = (li, lj) 8x8
    const int li = lane >> 3, lj = lane & 7;

    float4 fa = *(const float4*)(srcA);
    float4 fm = *(const float4*)(srcM);

    const f32x2 one2 = {1.0f, 1.0f};
    f32x2 accA[2] = {}, accB[2] = {};    // rows 2li / 2li+1, slots 0/1

    #pragma unroll 1
    for (int c = 0; c < 8; ++c) {        // 8 chunks x 16 h
        const int hh = c * 16;
        *(float4*)&Ea[wv][sr][sc] = fa;  // wave-private; in-order DS pipe
        *(float4*)&Em[wv][sr][sc] = fm;
        if (c < 7) {
            fa = *(const float4*)(srcA + hh + 16);
            fm = *(const float4*)(srcM + hh + 16);
        }
        #pragma unroll
        for (int hq = 0; hq < 4; ++hq) {
            float4 e0 = *(const float4*)&Ea[wv][2 * li    ][hq * 4];
            float4 e1 = *(const float4*)&Ea[wv][2 * li + 1][hq * 4];
            float4 f0 = *(const float4*)&Em[wv][2 * lj    ][hq * 4];
            float4 f1 = *(const float4*)&Em[wv][2 * lj + 1][hq * 4];
            float4 w4 = *(const float4*)&wl[hb0 + hh + hq * 4];  // broadcast
            #define PKQUAD(DA, DB, WH, ACCA, ACCB)                   \
            {                                                        \
                f32x2 Q  = DA * DB;                                  \
                float pr = Q.x * Q.y;                                \
                float R  = fast_rcp(pr);                             \
                float RW = R * (WH);                                 \
                f32x2 T  = (f32x2){Q.y, Q.x} * RW;                   \
                ACCA = __builtin_elementwise_fma(T, DB, ACCA);       \
                ACCB = __builtin_elementwise_fma(T, DA, ACCB);       \
            }
            #define HSTEP(H, S)                                                     \
            {                                                                       \
                f32x2 F  = {f0.H, f1.H};                                            \
                f32x2 D0 = __builtin_elementwise_fma((f32x2){e0.H, e0.H}, F, one2); \
                f32x2 D1 = __builtin_elementwise_fma((f32x2){e1.H, e1.H}, F, one2); \
                PKQUAD(D0, D1, w4.H, accA[S], accB[S])                              \
            }
            HSTEP(x, 0) HSTEP(y, 1) HSTEP(z, 0) HSTEP(w, 1)
            #undef HSTEP
            #undef PKQUAD
        }
    }

    f32x2 s0 = accA[0] + accA[1];        // row 2li:   (j0, j1)
    f32x2 s1 = accB[0] + accB[1];        // row 2li+1: (j0, j1)

    // combine 4 h-quarters: waves 1..3 park partials in LDS overlay on Ea,
    // wave 0 sums and writes out.
    float* partial = (float*)Ea;
    __syncthreads();
    if (wv >= 1) {
        float* p = partial + (wv - 1) * 256 + lane * 4;
        p[0] = s0.x; p[1] = s0.y; p[2] = s1.x; p[3] = s1.y;
    }
    __syncthreads();
    if (wv == 0) {
        const float base = lsum + outBias[0];
        float t00 = s0.x, t01 = s0.y, t10 = s1.x, t11 = s1.y;
        #pragma unroll
        for (int q = 0; q < 3; ++q) {
            const float* p = partial + q * 256 + lane * 4;
            t00 += p[0]; t01 += p[1]; t10 += p[2]; t11 += p[3];
        }
        const int gi = i0 + 2 * li, gj = j0 + 2 * lj;
        float2 o0, o1;
        o0.x = fmaf(-2.f, t00, base);
        o0.y = fmaf(-2.f, t01, base);
        o1.x = fmaf(-2.f, t10, base);
        o1.y = fmaf(-2.f, t11, base);
        *(float2*)&out[gi * TT + gj]       = o0;
        *(float2*)&out[(gi + 1) * TT + gj] = o1;
    }
}

extern "C" void kernel_launch(void* const* d_in, const int* in_sizes, int n_in,
                              void* d_out, int out_size, void* d_ws, size_t ws_size,
                              hipStream_t stream) {
    const float* x        = (const float*)d_in[0];
    const float* foh      = (const float*)d_in[1];
    const float* fom      = (const float*)d_in[2];
    const float* catBias  = (const float*)d_in[3];
    const float* hid2     = (const float*)d_in[4];
    const float* hid2Bias = (const float*)d_in[5];
    const float* outLayer = (const float*)d_in[6];
    const float* outBias  = (const float*)d_in[7];
    float* out = (float*)d_out;

    char* wsb = (char*)d_ws;
    float*  pw  = (float*)(wsb);                        // 768*1024*4
    ushort* act = (ushort*)(wsb + 3145728);             // 768*1024*2
    ushort* xb  = (ushort*)(wsb + 4718592);             // 768*512*2
    ushort* b1t = (ushort*)(wsb + 5505024);             // 1024*512*2
    ushort* h2t = (ushort*)(wsb + 6553600);             // 512*1024*2

    k_prep <<<dim3(1408),    64, 0, stream>>>(x, foh, fom, hid2, xb, b1t, h2t);
    k_gemm1<<<dim3(32, 24), 128, 0, stream>>>(xb, b1t, catBias, act);
    k_gemm2<<<dim3(32, 24), 128, 0, stream>>>(act, h2t, hid2Bias, pw);
    k_pair <<<dim3(2304),   256, 0, stream>>>(pw, outLayer, outBias, out);
}